// Round 1
// baseline (539.576 us; speedup 1.0000x reference)
//
#include <hip/hip_runtime.h>

#define NB 64
#define NT 512
#define NE 128
#define NF 128
#define NC 13
#define MT 64          // t-rows per block
#define APAD 136       // padded LDS stride for A tile (136%32=8 -> conflict-free)

__global__ __launch_bounds__(256)
void pot_kernel(const int* __restrict__ input_char,
                const int* __restrict__ input_script,
                const float* __restrict__ char_emb,
                const float* __restrict__ uscript_emb,
                const float* __restrict__ dense_w,
                const float* __restrict__ dense_b,
                const float* __restrict__ left_b,
                const float* __restrict__ right_b,
                const float* __restrict__ cw1, const float* __restrict__ cb1,
                const float* __restrict__ cw2, const float* __restrict__ cb2,
                const float* __restrict__ cw3, const float* __restrict__ cb3,
                const float* __restrict__ cw4, const float* __restrict__ cb4,
                const float* __restrict__ cw5, const float* __restrict__ cb5,
                float* __restrict__ out_pot)
{
    __shared__ float A_lds[68 * APAD];    // emb rows t0-2 .. t0+65
    __shared__ float W_lds[32 * 128];     // current weight chunk [e][f]
    __shared__ float dw_lds[128 * 13];    // dense_w slice for current f-block
    __shared__ float pot_lds[64 * 13];    // accumulated potentials

    const int tid = threadIdx.x;
    const int bx  = blockIdx.x;
    const int b   = bx >> 3;
    const int t0  = (bx & 7) * MT;
    const int tx  = tid & 15;   // col group: f' = tx*8 .. tx*8+7
    const int ty  = tid >> 4;   // row group: t rows ty*4 .. ty*4+3

    for (int i = tid; i < 64 * 13; i += 256) pot_lds[i] = 0.f;

    // ---- stage A tile (zero-padded halo) ----
    {
        const int* ic = input_char + b * NT;
        for (int i = tid; i < 68 * 32; i += 256) {
            int row = i >> 5;
            int c4  = (i & 31) << 2;
            int t   = t0 - 2 + row;
            float4 v = make_float4(0.f, 0.f, 0.f, 0.f);
            if (t >= 0 && t < NT) {
                int ch = ic[t];
                v = *reinterpret_cast<const float4*>(char_emb + ch * NE + c4);
            }
            *reinterpret_cast<float4*>(&A_lds[row * APAD + c4]) = v;
        }
    }
    __syncthreads();

    const float* cws[5] = {cw1, cw2, cw3, cw4, cw5};
    const float* cbs[5] = {cb1, cb2, cb3, cb4, cb5};

    for (int fb = 0; fb < 5; ++fb) {
        const int k  = fb + 1;
        const int j0 = 2 - ((k - 1) >> 1);   // combined-tap offset
        const float* cw = cws[fb];

        float acc[4][8];
        #pragma unroll
        for (int r = 0; r < 4; ++r)
            #pragma unroll
            for (int c = 0; c < 8; ++c) acc[r][c] = 0.f;

        for (int jj = 0; jj < k; ++jj) {
            const int j = j0 + jj;
            for (int e0 = 0; e0 < NE; e0 += 32) {
                // stage W chunk [32 e][128 f]
                for (int i = tid; i < 32 * 32; i += 256) {
                    int er = i >> 5;
                    int f4 = (i & 31) << 2;
                    *reinterpret_cast<float4*>(&W_lds[er * 128 + f4]) =
                        *reinterpret_cast<const float4*>(cw + (jj * NE + e0 + er) * NF + f4);
                }
                __syncthreads();
                #pragma unroll 4
                for (int e = 0; e < 32; ++e) {
                    float4 b01 = *reinterpret_cast<const float4*>(&W_lds[e * 128 + tx * 8]);
                    float4 b23 = *reinterpret_cast<const float4*>(&W_lds[e * 128 + tx * 8 + 4]);
                    float bb[8] = {b01.x, b01.y, b01.z, b01.w, b23.x, b23.y, b23.z, b23.w};
                    #pragma unroll
                    for (int rr = 0; rr < 4; ++rr) {
                        float a = A_lds[(ty * 4 + rr + j) * APAD + e0 + e];
                        #pragma unroll
                        for (int cc = 0; cc < 8; ++cc)
                            acc[rr][cc] = fmaf(a, bb[cc], acc[rr][cc]);
                    }
                }
                __syncthreads();
            }
        }

        // stage dense_w slice for this f-block
        for (int i = tid; i < 128 * 13; i += 256)
            dw_lds[i] = dense_w[fb * 128 * 13 + i];
        __syncthreads();

        // ReLU(conv+bias) folded into 640->13 reduction
        const float* cb = cbs[fb];
        float part[4][13];
        #pragma unroll
        for (int r = 0; r < 4; ++r)
            #pragma unroll
            for (int c = 0; c < NC; ++c) part[r][c] = 0.f;

        #pragma unroll
        for (int cc = 0; cc < 8; ++cc) {
            float bias = cb[tx * 8 + cc];
            float dwv[13];
            #pragma unroll
            for (int c = 0; c < NC; ++c) dwv[c] = dw_lds[(tx * 8 + cc) * 13 + c];
            #pragma unroll
            for (int rr = 0; rr < 4; ++rr) {
                float v = fmaxf(acc[rr][cc] + bias, 0.f);
                #pragma unroll
                for (int c = 0; c < NC; ++c)
                    part[rr][c] = fmaf(v, dwv[c], part[rr][c]);
            }
        }

        // butterfly-reduce across the 16 tx lanes (within each 16-lane group)
        #pragma unroll
        for (int off = 8; off >= 1; off >>= 1) {
            #pragma unroll
            for (int rr = 0; rr < 4; ++rr)
                #pragma unroll
                for (int c = 0; c < NC; ++c)
                    part[rr][c] += __shfl_xor(part[rr][c], off);
        }
        if (tx == 0) {
            #pragma unroll
            for (int rr = 0; rr < 4; ++rr)
                #pragma unroll
                for (int c = 0; c < NC; ++c)
                    pot_lds[(ty * 4 + rr) * 13 + c] += part[rr][c];
        }
        __syncthreads();
    }

    // ---- final epilogue: uemb + dense_b + boundary, store pot ----
    if (tid < MT) {
        int t = t0 + tid;
        int us = input_script[b * NT + t];
        const float* ue = uscript_emb + us * 16;
        float pc[13];
        #pragma unroll
        for (int c = 0; c < NC; ++c) pc[c] = pot_lds[tid * 13 + c] + dense_b[c];
        #pragma unroll
        for (int u = 0; u < 16; ++u) {
            float uv = ue[u];
            #pragma unroll
            for (int c = 0; c < NC; ++c)
                pc[c] = fmaf(uv, dense_w[(640 + u) * 13 + c], pc[c]);
        }
        if (t == 0)
            for (int c = 0; c < NC; ++c) pc[c] += left_b[c];
        if (t == NT - 1)
            for (int c = 0; c < NC; ++c) pc[c] += right_b[c];
        float* dst = out_pot + (b * NT + t) * 13;
        for (int c = 0; c < NC; ++c) dst[c] = pc[c];
    }
}

__global__ __launch_bounds__(64)
void viterbi_kernel(const float* __restrict__ pot,
                    const float* __restrict__ trans,
                    float* __restrict__ out_dec,
                    float* __restrict__ out_seq,
                    float* __restrict__ out_trans)
{
    __shared__ unsigned char bp[NT * 16];
    const int b = blockIdx.x;
    const int lane = threadIdx.x;

    float tc[13];
    int myc = (lane < NC) ? lane : 0;
    #pragma unroll
    for (int p = 0; p < NC; ++p) tc[p] = trans[p * NC + myc];

    const float* pb = pot + b * NT * NC;
    float s = (lane < NC) ? pb[lane] : -1e30f;

    for (int t = 1; t < NT; ++t) {
        float pv = (lane < NC) ? pb[t * NC + lane] : 0.f;
        float best = -1e30f;
        int bi = 0;
        #pragma unroll
        for (int p = 0; p < NC; ++p) {
            float v = __shfl(s, p) + tc[p];
            if (v > best) { best = v; bi = p; }   // strict > keeps first max (jnp.argmax)
        }
        s = best + pv;
        if (lane < NC) bp[t * 16 + lane] = (unsigned char)bi;
    }

    // argmax of final state over lanes 0..12
    float best = -1e30f;
    int last = 0;
    #pragma unroll
    for (int p = 0; p < NC; ++p) {
        float v = __shfl(s, p);
        if (v > best) { best = v; last = p; }
    }

    if (lane == 0) {
        float* dec = out_dec + b * NT;
        int tag = last;
        dec[NT - 1] = (float)tag;
        for (int t = NT - 1; t >= 1; --t) {
            tag = bp[t * 16 + tag];
            dec[t - 1] = (float)tag;
        }
        out_seq[b] = (float)NT;
    }
    if (b == 0) {
        for (int i = lane; i < NC * NC; i += 64) out_trans[i] = trans[i];
    }
}

extern "C" void kernel_launch(void* const* d_in, const int* in_sizes, int n_in,
                              void* d_out, int out_size, void* d_ws, size_t ws_size,
                              hipStream_t stream) {
    const int*   input_char   = (const int*)d_in[0];
    const int*   input_script = (const int*)d_in[1];
    // d_in[2] = input_mask (all ones by construction; unused)
    const float* char_emb     = (const float*)d_in[3];
    const float* uscript_emb  = (const float*)d_in[4];
    const float* dense_w      = (const float*)d_in[5];
    const float* dense_b      = (const float*)d_in[6];
    const float* trans        = (const float*)d_in[7];
    const float* left_b       = (const float*)d_in[8];
    const float* right_b      = (const float*)d_in[9];
    const float* cw1 = (const float*)d_in[10];
    const float* cb1 = (const float*)d_in[11];
    const float* cw2 = (const float*)d_in[12];
    const float* cb2 = (const float*)d_in[13];
    const float* cw3 = (const float*)d_in[14];
    const float* cb3 = (const float*)d_in[15];
    const float* cw4 = (const float*)d_in[16];
    const float* cb4 = (const float*)d_in[17];
    const float* cw5 = (const float*)d_in[18];
    const float* cb5 = (const float*)d_in[19];

    float* out       = (float*)d_out;
    float* out_dec   = out;                       // [B,T] decoded tags (as float)
    float* out_pot   = out + NB * NT;             // [B,T,C]
    float* out_seq   = out_pot + NB * NT * NC;    // [B]
    float* out_trans = out_seq + NB;              // [C,C]

    hipLaunchKernelGGL(pot_kernel, dim3(NB * (NT / MT)), dim3(256), 0, stream,
                       input_char, input_script, char_emb, uscript_emb,
                       dense_w, dense_b, left_b, right_b,
                       cw1, cb1, cw2, cb2, cw3, cb3, cw4, cb4, cw5, cb5,
                       out_pot);

    hipLaunchKernelGGL(viterbi_kernel, dim3(NB), dim3(64), 0, stream,
                       out_pot, trans, out_dec, out_seq, out_trans);
}

// Round 2
// 535.905 us; speedup vs baseline: 1.0068x; 1.0068x over previous
//
#include <hip/hip_runtime.h>

#define NB 64
#define NT 512
#define NE 128
#define NF 128
#define NC 13
#define MT 32            // t-rows per block
#define AROWS 36         // rows t0-2 .. t0+33
#define APAD 136         // 136%32=8 -> conflict-free broadcast rows

__global__ __launch_bounds__(256, 4)
void pot_kernel(const int* __restrict__ input_char,
                const int* __restrict__ input_script,
                const float* __restrict__ char_emb,
                const float* __restrict__ uscript_emb,
                const float* __restrict__ dense_w,
                const float* __restrict__ dense_b,
                const float* __restrict__ left_b,
                const float* __restrict__ right_b,
                const float* __restrict__ cw1, const float* __restrict__ cb1,
                const float* __restrict__ cw2, const float* __restrict__ cb2,
                const float* __restrict__ cw3, const float* __restrict__ cb3,
                const float* __restrict__ cw4, const float* __restrict__ cb4,
                const float* __restrict__ cw5, const float* __restrict__ cb5,
                float* __restrict__ out_pot)
{
    __shared__ __align__(16) float A_lds[AROWS * APAD];   // emb rows t0-2 .. t0+33
    __shared__ float dw_lds[128 * 13];                    // dense_w slice for current f-block
    __shared__ float pot_lds[MT * 13];

    const int tid = threadIdx.x;
    const int bx  = blockIdx.x;
    const int b   = bx >> 4;
    const int t0  = (bx & 15) * MT;
    const int tx  = tid & 15;   // f-cols: tx*4+{0..3} and 64+tx*4+{0..3}
    const int ty  = tid >> 4;   // rows ty*2, ty*2+1

    for (int i = tid; i < MT * 13; i += 256) pot_lds[i] = 0.f;

    // ---- stage A tile (zero-padded halo) ----
    {
        const int* ic = input_char + b * NT;
        for (int i = tid; i < AROWS * 32; i += 256) {
            int row = i >> 5;
            int c4  = (i & 31) << 2;
            int t   = t0 - 2 + row;
            float4 v = make_float4(0.f, 0.f, 0.f, 0.f);
            if (t >= 0 && t < NT) {
                int ch = ic[t];
                v = *reinterpret_cast<const float4*>(char_emb + ch * NE + c4);
            }
            *reinterpret_cast<float4*>(&A_lds[row * APAD + c4]) = v;
        }
    }
    __syncthreads();

    const float* cws[5] = {cw1, cw2, cw3, cw4, cw5};
    const float* cbs[5] = {cb1, cb2, cb3, cb4, cb5};

    #pragma unroll 1
    for (int fb = 0; fb < 5; ++fb) {
        const int k  = fb + 1;
        const int j0 = 2 - ((k - 1) >> 1);
        const float* cw = cws[fb];

        float acc[2][8];
        #pragma unroll
        for (int r = 0; r < 2; ++r)
            #pragma unroll
            for (int c = 0; c < 8; ++c) acc[r][c] = 0.f;

        #pragma unroll 1
        for (int jj = 0; jj < k; ++jj) {
            const float* wp    = cw + jj * NE * NF + tx * 4;  // + e*128 (+64 for hi half)
            const float* arow0 = &A_lds[(ty * 2 + j0 + jj) * APAD];
            const float* arow1 = arow0 + APAD;

            #pragma unroll 2
            for (int e4 = 0; e4 < NE; e4 += 4) {
                float4 a0 = *reinterpret_cast<const float4*>(arow0 + e4);
                float4 a1 = *reinterpret_cast<const float4*>(arow1 + e4);
                #pragma unroll
                for (int ee = 0; ee < 4; ++ee) {
                    float4 w0 = *reinterpret_cast<const float4*>(wp + (e4 + ee) * NF);
                    float4 w1 = *reinterpret_cast<const float4*>(wp + (e4 + ee) * NF + 64);
                    float av0 = (&a0.x)[ee];
                    float av1 = (&a1.x)[ee];
                    acc[0][0] = fmaf(av0, w0.x, acc[0][0]);
                    acc[0][1] = fmaf(av0, w0.y, acc[0][1]);
                    acc[0][2] = fmaf(av0, w0.z, acc[0][2]);
                    acc[0][3] = fmaf(av0, w0.w, acc[0][3]);
                    acc[0][4] = fmaf(av0, w1.x, acc[0][4]);
                    acc[0][5] = fmaf(av0, w1.y, acc[0][5]);
                    acc[0][6] = fmaf(av0, w1.z, acc[0][6]);
                    acc[0][7] = fmaf(av0, w1.w, acc[0][7]);
                    acc[1][0] = fmaf(av1, w0.x, acc[1][0]);
                    acc[1][1] = fmaf(av1, w0.y, acc[1][1]);
                    acc[1][2] = fmaf(av1, w0.z, acc[1][2]);
                    acc[1][3] = fmaf(av1, w0.w, acc[1][3]);
                    acc[1][4] = fmaf(av1, w1.x, acc[1][4]);
                    acc[1][5] = fmaf(av1, w1.y, acc[1][5]);
                    acc[1][6] = fmaf(av1, w1.z, acc[1][6]);
                    acc[1][7] = fmaf(av1, w1.w, acc[1][7]);
                }
            }
        }

        // stage dense_w slice for this f-block
        __syncthreads();
        for (int i = tid; i < 128 * 13; i += 256)
            dw_lds[i] = dense_w[fb * 128 * 13 + i];
        __syncthreads();

        // ReLU(conv+bias) folded into 128->13 partial reduction
        const float* cb = cbs[fb];
        float part[2][13];
        #pragma unroll
        for (int r = 0; r < 2; ++r)
            #pragma unroll
            for (int c = 0; c < NC; ++c) part[r][c] = 0.f;

        #pragma unroll
        for (int cc = 0; cc < 8; ++cc) {
            int f = (cc < 4) ? (tx * 4 + cc) : (64 + tx * 4 + (cc - 4));
            float bias = cb[f];
            float dwv[13];
            #pragma unroll
            for (int c = 0; c < NC; ++c) dwv[c] = dw_lds[f * 13 + c];
            #pragma unroll
            for (int rr = 0; rr < 2; ++rr) {
                float v = fmaxf(acc[rr][cc] + bias, 0.f);
                #pragma unroll
                for (int c = 0; c < NC; ++c)
                    part[rr][c] = fmaf(v, dwv[c], part[rr][c]);
            }
        }

        // reduce across the 16 tx lanes
        #pragma unroll
        for (int off = 8; off >= 1; off >>= 1) {
            #pragma unroll
            for (int rr = 0; rr < 2; ++rr)
                #pragma unroll
                for (int c = 0; c < NC; ++c)
                    part[rr][c] += __shfl_xor(part[rr][c], off);
        }
        if (tx == 0) {
            #pragma unroll
            for (int rr = 0; rr < 2; ++rr)
                #pragma unroll
                for (int c = 0; c < NC; ++c)
                    pot_lds[(ty * 2 + rr) * 13 + c] += part[rr][c];
        }
        __syncthreads();
    }

    // ---- final epilogue: uemb + dense_b + boundary, store pot ----
    // stage uemb rows of dense_w (rows 640..655) into dw_lds[0..207]
    for (int i = tid; i < 16 * 13; i += 256) dw_lds[i] = dense_w[640 * 13 + i];
    __syncthreads();

    if (tid < MT) {
        int t = t0 + tid;
        int us = input_script[b * NT + t];
        const float* ue = uscript_emb + us * 16;
        float pc[13];
        #pragma unroll
        for (int c = 0; c < NC; ++c) pc[c] = pot_lds[tid * 13 + c] + dense_b[c];
        #pragma unroll
        for (int u = 0; u < 16; ++u) {
            float uv = ue[u];
            #pragma unroll
            for (int c = 0; c < NC; ++c)
                pc[c] = fmaf(uv, dw_lds[u * 13 + c], pc[c]);
        }
        if (t == 0)
            for (int c = 0; c < NC; ++c) pc[c] += left_b[c];
        if (t == NT - 1)
            for (int c = 0; c < NC; ++c) pc[c] += right_b[c];
        float* dst = out_pot + (b * NT + t) * 13;
        for (int c = 0; c < NC; ++c) dst[c] = pc[c];
    }
}

// One block per batch. Stage pot in LDS; forward scan (values only, no bp);
// recompute backpointers chunk-parallel from stored state rows; stitch.
__global__ __launch_bounds__(256)
void viterbi_kernel(const float* __restrict__ pot,
                    const float* __restrict__ trans,
                    float* __restrict__ out_dec,
                    float* __restrict__ out_seq,
                    float* __restrict__ out_trans)
{
    __shared__ __align__(16) float s_lds[NT * NC];       // pot rows, overwritten by state rows
    __shared__ float t_lds[NC * NC];
    __shared__ unsigned char path_lds[16 * 13 * 32];
    __shared__ unsigned char entry_lds[16 * 13];
    __shared__ int chunk_e[16];

    const int b   = blockIdx.x;
    const int tid = threadIdx.x;

    // stage pot[b] (6656 floats, 16B aligned) and trans
    {
        const float4* src = reinterpret_cast<const float4*>(pot + b * NT * NC);
        float4* dst = reinterpret_cast<float4*>(s_lds);
        for (int i = tid; i < NT * NC / 4; i += 256) dst[i] = src[i];
        for (int i = tid; i < NC * NC; i += 256) t_lds[i] = trans[i];
    }
    __syncthreads();

    // ---- forward scan, wave 0, lane c holds s[c]; rows become state vectors ----
    if (tid < 64) {
        const int c = tid;
        const bool act = c < NC;
        float tc[13];
        #pragma unroll
        for (int p = 0; p < NC; ++p) tc[p] = t_lds[p * NC + (act ? c : 0)];
        float s = act ? s_lds[c] : -1e30f;

        for (int t = 1; t < NT; ++t) {
            float v[13];
            #pragma unroll
            for (int p = 0; p < NC; ++p) v[p] = __shfl(s, p) + tc[p];
            float m0 = fmaxf(fmaxf(v[0], v[1]), fmaxf(v[2], v[3]));
            float m1 = fmaxf(fmaxf(v[4], v[5]), fmaxf(v[6], v[7]));
            float m2 = fmaxf(fmaxf(v[8], v[9]), fmaxf(v[10], v[11]));
            float best = fmaxf(fmaxf(m0, m1), fmaxf(m2, v[12]));
            float pv = act ? s_lds[t * NC + c] : 0.f;
            s = best + pv;
            if (act) s_lds[t * NC + c] = s;
        }
    }
    __syncthreads();

    // ---- speculative chunk-parallel backpointer recomputation ----
    // thread (chunk, e): assume tag at t = 32*chunk+31 is e; walk back.
    if (tid < 16 * 13) {
        const int chunk = tid / 13;
        const int e     = tid - chunk * 13;
        unsigned char* path = &path_lds[(chunk * 13 + e) * 32];
        int cur = e;
        path[31] = (unsigned char)e;
        for (int tl = 31; tl >= 1; --tl) {
            const float* srow = &s_lds[(chunk * 32 + tl - 1) * NC];
            float best = -1e30f; int bi = 0;
            #pragma unroll
            for (int p = 0; p < NC; ++p) {
                float v = srow[p] + t_lds[p * NC + cur];
                if (v > best) { best = v; bi = p; }   // first-max (jnp.argmax)
            }
            cur = bi;
            path[tl - 1] = (unsigned char)cur;
        }
        if (chunk > 0) {
            const float* srow = &s_lds[(chunk * 32 - 1) * NC];
            float best = -1e30f; int bi = 0;
            #pragma unroll
            for (int p = 0; p < NC; ++p) {
                float v = srow[p] + t_lds[p * NC + cur];
                if (v > best) { best = v; bi = p; }
            }
            entry_lds[chunk * 13 + e] = (unsigned char)bi;
        }
    }
    __syncthreads();

    // ---- stitch ----
    if (tid == 0) {
        float best = -1e30f; int last = 0;
        for (int c = 0; c < NC; ++c) {
            float v = s_lds[(NT - 1) * NC + c];
            if (v > best) { best = v; last = c; }
        }
        chunk_e[15] = last;
        for (int i = 15; i >= 1; --i)
            chunk_e[i - 1] = entry_lds[i * 13 + chunk_e[i]];
    }
    __syncthreads();

    // ---- emit ----
    float* dec = out_dec + b * NT;
    for (int t = tid; t < NT; t += 256) {
        int ck = t >> 5;
        dec[t] = (float)path_lds[(ck * 13 + chunk_e[ck]) * 32 + (t & 31)];
    }
    if (tid == 0) out_seq[b] = (float)NT;
    if (b == 0) {
        for (int i = tid; i < NC * NC; i += 256) out_trans[i] = trans[i];
    }
}

extern "C" void kernel_launch(void* const* d_in, const int* in_sizes, int n_in,
                              void* d_out, int out_size, void* d_ws, size_t ws_size,
                              hipStream_t stream) {
    const int*   input_char   = (const int*)d_in[0];
    const int*   input_script = (const int*)d_in[1];
    const float* char_emb     = (const float*)d_in[3];
    const float* uscript_emb  = (const float*)d_in[4];
    const float* dense_w      = (const float*)d_in[5];
    const float* dense_b      = (const float*)d_in[6];
    const float* trans        = (const float*)d_in[7];
    const float* left_b       = (const float*)d_in[8];
    const float* right_b      = (const float*)d_in[9];
    const float* cw1 = (const float*)d_in[10];
    const float* cb1 = (const float*)d_in[11];
    const float* cw2 = (const float*)d_in[12];
    const float* cb2 = (const float*)d_in[13];
    const float* cw3 = (const float*)d_in[14];
    const float* cb3 = (const float*)d_in[15];
    const float* cw4 = (const float*)d_in[16];
    const float* cb4 = (const float*)d_in[17];
    const float* cw5 = (const float*)d_in[18];
    const float* cb5 = (const float*)d_in[19];

    float* out       = (float*)d_out;
    float* out_dec   = out;                       // [B,T] decoded tags (as float)
    float* out_pot   = out + NB * NT;             // [B,T,C]
    float* out_seq   = out_pot + NB * NT * NC;    // [B]
    float* out_trans = out_seq + NB;              // [C,C]

    hipLaunchKernelGGL(pot_kernel, dim3(NB * (NT / MT)), dim3(256), 0, stream,
                       input_char, input_script, char_emb, uscript_emb,
                       dense_w, dense_b, left_b, right_b,
                       cw1, cb1, cw2, cb2, cw3, cb3, cw4, cb4, cw5, cb5,
                       out_pot);

    hipLaunchKernelGGL(viterbi_kernel, dim3(NB), dim3(256), 0, stream,
                       out_pot, trans, out_dec, out_seq, out_trans);
}

// Round 4
// 191.378 us; speedup vs baseline: 2.8194x; 2.8002x over previous
//
#include <hip/hip_runtime.h>

#define NB 64
#define NT 512
#define NC 13
#define AP 136    // A row stride (ush): bank shift 4/row -> 2-way max (free)
#define WP 72     // W row stride (ush): 16B-aligned rows, 2-way max

typedef short s8v __attribute__((ext_vector_type(8)));
typedef float f4v __attribute__((ext_vector_type(4)));
typedef unsigned short ush;
typedef unsigned int u32;

__device__ __forceinline__ ush f2bf(float f){
    union { float f; u32 u; } v; v.f = f;
    u32 r = v.u + 0x7fffu + ((v.u >> 16) & 1u);
    return (ush)(r >> 16);
}
__device__ __forceinline__ float bf2f(ush h){
    union { u32 u; float f; } v; v.u = ((u32)h) << 16; return v.f;
}

// 256 blocks (b = bx>>2, t0 = (bx&3)*128), 512 threads = 8 waves.
// wave: tg = wid>>2 (t-half), fg = wid&3 (f-quarter); tile 64t x 32f.
// 30 units = (tap ut 0..14) x (e-half). W split fp32->bf16 hi/lo in-kernel.
__global__ __launch_bounds__(512)
void pot_kernel(const int* __restrict__ input_char,
                const int* __restrict__ input_script,
                const float* __restrict__ char_emb,
                const float* __restrict__ uscript_emb,
                const float* __restrict__ dense_w,
                const float* __restrict__ dense_b,
                const float* __restrict__ left_b,
                const float* __restrict__ right_b,
                const float* __restrict__ cw1, const float* __restrict__ cb1,
                const float* __restrict__ cw2, const float* __restrict__ cb2,
                const float* __restrict__ cw3, const float* __restrict__ cb3,
                const float* __restrict__ cw4, const float* __restrict__ cb4,
                const float* __restrict__ cw5, const float* __restrict__ cb5,
                float* __restrict__ out_pot)
{
    __shared__ __align__(16) ush smem[71744];           // 143488 B
    ush* Ah     = smem;                                 // 132 x AP
    ush* Al     = smem + 17952;
    ush* Wh     = smem + 35904;                         // 128 x WP
    ush* Wl     = smem + 45120;
    ush* feat_h = smem + 54336;                         // 64 x AP
    ush* feat_l = smem + 63040;
    // epilogue aliases (only live when Wh/Wl are dead, guarded by barriers):
    float* dwlds = (float*)(smem + 35904);              // 128*13 fp32
    float* dwue  = (float*)(smem + 39232);              // 16*13 fp32
    float* uebt  = (float*)(smem + 39648);              // 16*128 fp32

    const int tid  = threadIdx.x;
    const int lane = tid & 63;
    const int wid  = tid >> 6;
    const int tg   = wid >> 2;
    const int fg   = wid & 3;
    const int lr   = lane & 15;
    const int lq   = lane >> 4;
    const int bb   = blockIdx.x >> 2;
    const int t0   = (blockIdx.x & 3) << 7;

    // ---- stage A: emb rows t0-2 .. t0+129, fp32 -> bf16 hi/lo, padded ----
    for (int i = tid; i < 132*16; i += 512) {
        int row = i >> 4, s = (i & 15) << 3;
        int t = t0 + row - 2;
        uint4 hv = {0,0,0,0}, lv = {0,0,0,0};
        if (t >= 0 && t < NT) {
            int ch = input_char[bb*NT + t];
            const float* src = char_emb + ch*128 + s;
            float4 x0 = *(const float4*)src;
            float4 x1 = *(const float4*)(src + 4);
            float fs[8] = {x0.x,x0.y,x0.z,x0.w,x1.x,x1.y,x1.z,x1.w};
            ush h[8], l[8];
            #pragma unroll
            for (int q = 0; q < 8; ++q) {
                h[q] = f2bf(fs[q]);
                l[q] = f2bf(fs[q] - bf2f(h[q]));
            }
            hv.x = h[0] | ((u32)h[1]<<16); hv.y = h[2] | ((u32)h[3]<<16);
            hv.z = h[4] | ((u32)h[5]<<16); hv.w = h[6] | ((u32)h[7]<<16);
            lv.x = l[0] | ((u32)l[1]<<16); lv.y = l[2] | ((u32)l[3]<<16);
            lv.z = l[4] | ((u32)l[5]<<16); lv.w = l[6] | ((u32)l[7]<<16);
        }
        *(uint4*)&Ah[row*AP + s] = hv;
        *(uint4*)&Al[row*AP + s] = lv;
    }

    const float* cws[5] = {cw1, cw2, cw3, cw4, cw5};
    const float* cbs[5] = {cb1, cb2, cb3, cb4, cb5};

    f4v cacc[4][2];
    #pragma unroll
    for (int mt = 0; mt < 4; ++mt)
        #pragma unroll
        for (int nt = 0; nt < 2; ++nt) cacc[mt][nt] = (f4v){0.f,0.f,0.f,0.f};
    f4v dacc = (f4v){0.f,0.f,0.f,0.f};

    #pragma unroll 1
    for (int u = 0; u < 30; ++u) {
        int ut  = u >> 1, eh = u & 1;
        int fb  = ut<1?0: ut<3?1: ut<6?2: ut<10?3:4;
        int jj  = ut - fb*(fb+1)/2;
        int jsh = (2 - (fb >> 1)) + jj;
        const float* cw = cws[fb] + (jj*128 + eh*64)*128;

        // ---- stage W unit: fp32 [e][f] -> bf16 hi/lo LDS [f][e], padded ----
        __syncthreads();   // prior readers of Wh/Wl/dwlds done
        for (int g = tid; g < 1024; g += 512) {
            int f = g & 127, e8 = (g >> 7) << 3;
            float v[8];
            #pragma unroll
            for (int q = 0; q < 8; ++q) v[q] = cw[(e8 + q)*128 + f];
            ush h8[8], l8[8];
            #pragma unroll
            for (int q = 0; q < 8; ++q) {
                h8[q] = f2bf(v[q]);
                l8[q] = f2bf(v[q] - bf2f(h8[q]));
            }
            uint4 hv, lv;
            hv.x = h8[0] | ((u32)h8[1]<<16); hv.y = h8[2] | ((u32)h8[3]<<16);
            hv.z = h8[4] | ((u32)h8[5]<<16); hv.w = h8[6] | ((u32)h8[7]<<16);
            lv.x = l8[0] | ((u32)l8[1]<<16); lv.y = l8[2] | ((u32)l8[3]<<16);
            lv.z = l8[4] | ((u32)l8[5]<<16); lv.w = l8[6] | ((u32)l8[7]<<16);
            *(uint4*)&Wh[f*WP + e8] = hv;
            *(uint4*)&Wl[f*WP + e8] = lv;
        }
        __syncthreads();

        // ---- conv MFMA: 48 per wave ----
        #pragma unroll
        for (int kk = 0; kk < 2; ++kk) {
            int ko = kk*32 + (lq << 3);
            s8v bh[2], bl[2];
            #pragma unroll
            for (int nt = 0; nt < 2; ++nt) {
                int frow = fg*32 + nt*16 + lr;
                bh[nt] = *(const s8v*)&Wh[frow*WP + ko];
                bl[nt] = *(const s8v*)&Wl[frow*WP + ko];
            }
            #pragma unroll
            for (int mt = 0; mt < 4; ++mt) {
                int row = tg*64 + mt*16 + lr + jsh;
                int ai  = row*AP + eh*64 + ko;
                s8v ah = *(const s8v*)&Ah[ai];
                s8v al = *(const s8v*)&Al[ai];
                #pragma unroll
                for (int nt = 0; nt < 2; ++nt) {
                    cacc[mt][nt] = __builtin_amdgcn_mfma_f32_16x16x32_bf16(ah, bh[nt], cacc[mt][nt], 0,0,0);
                    cacc[mt][nt] = __builtin_amdgcn_mfma_f32_16x16x32_bf16(ah, bl[nt], cacc[mt][nt], 0,0,0);
                    cacc[mt][nt] = __builtin_amdgcn_mfma_f32_16x16x32_bf16(al, bh[nt], cacc[mt][nt], 0,0,0);
                }
            }
        }

        // ---- end of an f-block: ReLU -> feat (bf16 hi/lo) -> dense MFMA ----
        if (u == 1 || u == 5 || u == 11 || u == 19 || u == 29) {
            __syncthreads();   // conv reads of Wh/Wl done; safe to alias
            for (int i = tid; i < 128*13; i += 512)
                dwlds[i] = dense_w[fb*128*13 + i];
            if (fb == 4) {
                for (int i = tid; i < 16*13; i += 512)
                    dwue[i] = dense_w[640*13 + i];
                for (int i = tid; i < 2048; i += 512) {
                    int uu = i >> 7, tl = i & 127;
                    uebt[uu*128 + tl] = uscript_emb[input_script[bb*NT + t0 + tl]*16 + uu];
                }
            }
            __syncthreads();

            float cbv0 = cbs[fb][fg*32 + lr];
            float cbv1 = cbs[fb][fg*32 + 16 + lr];

            #pragma unroll 1
            for (int h = 0; h < 2; ++h) {
                if (tg == h) {
                    #pragma unroll
                    for (int mt = 0; mt < 4; ++mt)
                        #pragma unroll
                        for (int nt = 0; nt < 2; ++nt)
                            #pragma unroll
                            for (int r = 0; r < 4; ++r) {
                                float v = fmaxf(cacc[mt][nt][r] + (nt ? cbv1 : cbv0), 0.f);
                                int rw = mt*16 + (lq << 2) + r;       // local t in half
                                int f  = fg*32 + nt*16 + lr;
                                ush hh = f2bf(v);
                                feat_h[rw*AP + f] = hh;
                                feat_l[rw*AP + f] = f2bf(v - bf2f(hh));
                            }
                }
                __syncthreads();
                if (tg == h) {
                    int trow = fg*16 + lr;                            // local t in half
                    #pragma unroll
                    for (int kf = 0; kf < 4; ++kf) {
                        int f0 = kf*32 + (lq << 3);
                        float dv[8];
                        #pragma unroll
                        for (int q = 0; q < 8; ++q) dv[q] = dwlds[(f0 + q)*13 + lr];
                        s8v a2h, a2l;
                        #pragma unroll
                        for (int q = 0; q < 8; ++q) {
                            ush hh = f2bf(dv[q]);
                            a2h[q] = (short)hh;
                            a2l[q] = (short)f2bf(dv[q] - bf2f(hh));
                        }
                        s8v b2h = *(const s8v*)&feat_h[trow*AP + f0];
                        s8v b2l = *(const s8v*)&feat_l[trow*AP + f0];
                        dacc = __builtin_amdgcn_mfma_f32_16x16x32_bf16(a2h, b2h, dacc, 0,0,0);
                        dacc = __builtin_amdgcn_mfma_f32_16x16x32_bf16(a2h, b2l, dacc, 0,0,0);
                        dacc = __builtin_amdgcn_mfma_f32_16x16x32_bf16(a2l, b2h, dacc, 0,0,0);
                    }
                    if (fb == 4) {
                        int tloc  = tg*64 + fg*16 + lr;
                        int tglob = t0 + tloc;
                        float pc[4];
                        #pragma unroll
                        for (int r = 0; r < 4; ++r) pc[r] = dacc[r];
                        #pragma unroll
                        for (int uu = 0; uu < 16; ++uu) {
                            float uv = uebt[uu*128 + tloc];
                            #pragma unroll
                            for (int r = 0; r < 4; ++r) {
                                int c = (lq << 2) + r;
                                if (c < 13) pc[r] = fmaf(uv, dwue[uu*13 + c], pc[r]);
                            }
                        }
                        #pragma unroll
                        for (int r = 0; r < 4; ++r) {
                            int c = (lq << 2) + r;
                            if (c < 13) {
                                float v = pc[r] + dense_b[c];
                                if (tglob == 0)    v += left_b[c];
                                if (tglob == NT-1) v += right_b[c];
                                out_pot[(bb*NT + tglob)*13 + c] = v;
                            }
                        }
                    }
                }
                __syncthreads();
            }
            #pragma unroll
            for (int mt = 0; mt < 4; ++mt)
                #pragma unroll
                for (int nt = 0; nt < 2; ++nt) cacc[mt][nt] = (f4v){0.f,0.f,0.f,0.f};
        }
    }
}

// ---------------- viterbi (round-2 version, proven) ----------------
__global__ __launch_bounds__(256)
void viterbi_kernel(const float* __restrict__ pot,
                    const float* __restrict__ trans,
                    float* __restrict__ out_dec,
                    float* __restrict__ out_seq,
                    float* __restrict__ out_trans)
{
    __shared__ __align__(16) float s_lds[NT * NC];
    __shared__ float t_lds[NC * NC];
    __shared__ unsigned char path_lds[16 * 13 * 32];
    __shared__ unsigned char entry_lds[16 * 13];
    __shared__ int chunk_e[16];

    const int b   = blockIdx.x;
    const int tid = threadIdx.x;

    {
        const float4* src = reinterpret_cast<const float4*>(pot + b * NT * NC);
        float4* dst = reinterpret_cast<float4*>(s_lds);
        for (int i = tid; i < NT * NC / 4; i += 256) dst[i] = src[i];
        for (int i = tid; i < NC * NC; i += 256) t_lds[i] = trans[i];
    }
    __syncthreads();

    if (tid < 64) {
        const int c = tid;
        const bool act = c < NC;
        float tc[13];
        #pragma unroll
        for (int p = 0; p < NC; ++p) tc[p] = t_lds[p * NC + (act ? c : 0)];
        float s = act ? s_lds[c] : -1e30f;

        for (int t = 1; t < NT; ++t) {
            float v[13];
            #pragma unroll
            for (int p = 0; p < NC; ++p) v[p] = __shfl(s, p) + tc[p];
            float m0 = fmaxf(fmaxf(v[0], v[1]), fmaxf(v[2], v[3]));
            float m1 = fmaxf(fmaxf(v[4], v[5]), fmaxf(v[6], v[7]));
            float m2 = fmaxf(fmaxf(v[8], v[9]), fmaxf(v[10], v[11]));
            float best = fmaxf(fmaxf(m0, m1), fmaxf(m2, v[12]));
            float pv = act ? s_lds[t * NC + c] : 0.f;
            s = best + pv;
            if (act) s_lds[t * NC + c] = s;
        }
    }
    __syncthreads();

    if (tid < 16 * 13) {
        const int chunk = tid / 13;
        const int e     = tid - chunk * 13;
        unsigned char* path = &path_lds[(chunk * 13 + e) * 32];
        int cur = e;
        path[31] = (unsigned char)e;
        for (int tl = 31; tl >= 1; --tl) {
            const float* srow = &s_lds[(chunk * 32 + tl - 1) * NC];
            float best = -1e30f; int bi = 0;
            #pragma unroll
            for (int p = 0; p < NC; ++p) {
                float v = srow[p] + t_lds[p * NC + cur];
                if (v > best) { best = v; bi = p; }   // first-max (jnp.argmax)
            }
            cur = bi;
            path[tl - 1] = (unsigned char)cur;
        }
        if (chunk > 0) {
            const float* srow = &s_lds[(chunk * 32 - 1) * NC];
            float best = -1e30f; int bi = 0;
            #pragma unroll
            for (int p = 0; p < NC; ++p) {
                float v = srow[p] + t_lds[p * NC + cur];
                if (v > best) { best = v; bi = p; }
            }
            entry_lds[chunk * 13 + e] = (unsigned char)bi;
        }
    }
    __syncthreads();

    if (tid == 0) {
        float best = -1e30f; int last = 0;
        for (int c = 0; c < NC; ++c) {
            float v = s_lds[(NT - 1) * NC + c];
            if (v > best) { best = v; last = c; }
        }
        chunk_e[15] = last;
        for (int i = 15; i >= 1; --i)
            chunk_e[i - 1] = entry_lds[i * 13 + chunk_e[i]];
    }
    __syncthreads();

    float* dec = out_dec + b * NT;
    for (int t = tid; t < NT; t += 256) {
        int ck = t >> 5;
        dec[t] = (float)path_lds[(ck * 13 + chunk_e[ck]) * 32 + (t & 31)];
    }
    if (tid == 0) out_seq[b] = (float)NT;
    if (b == 0) {
        for (int i = tid; i < NC * NC; i += 256) out_trans[i] = trans[i];
    }
}

extern "C" void kernel_launch(void* const* d_in, const int* in_sizes, int n_in,
                              void* d_out, int out_size, void* d_ws, size_t ws_size,
                              hipStream_t stream) {
    const int*   input_char   = (const int*)d_in[0];
    const int*   input_script = (const int*)d_in[1];
    const float* char_emb     = (const float*)d_in[3];
    const float* uscript_emb  = (const float*)d_in[4];
    const float* dense_w      = (const float*)d_in[5];
    const float* dense_b      = (const float*)d_in[6];
    const float* trans        = (const float*)d_in[7];
    const float* left_b       = (const float*)d_in[8];
    const float* right_b      = (const float*)d_in[9];
    const float* cw1 = (const float*)d_in[10];
    const float* cb1 = (const float*)d_in[11];
    const float* cw2 = (const float*)d_in[12];
    const float* cb2 = (const float*)d_in[13];
    const float* cw3 = (const float*)d_in[14];
    const float* cb3 = (const float*)d_in[15];
    const float* cw4 = (const float*)d_in[16];
    const float* cb4 = (const float*)d_in[17];
    const float* cw5 = (const float*)d_in[18];
    const float* cb5 = (const float*)d_in[19];

    float* out       = (float*)d_out;
    float* out_dec   = out;                       // [B,T] decoded tags (as float)
    float* out_pot   = out + NB * NT;             // [B,T,C]
    float* out_seq   = out_pot + NB * NT * NC;    // [B]
    float* out_trans = out_seq + NB;              // [C,C]

    hipLaunchKernelGGL(pot_kernel, dim3(256), dim3(512), 0, stream,
                       input_char, input_script, char_emb, uscript_emb,
                       dense_w, dense_b, left_b, right_b,
                       cw1, cb1, cw2, cb2, cw3, cb3, cw4, cb4, cw5, cb5,
                       out_pot);

    hipLaunchKernelGGL(viterbi_kernel, dim3(NB), dim3(256), 0, stream,
                       out_pot, trans, out_dec, out_seq, out_trans);
}